// Round 19
// baseline (18.613 us; speedup 1.0000x reference)
//
#include <hip/hip_runtime.h>
#include <math.h>

#define PI_F 3.14159265358979323846f

typedef float    f32x4 __attribute__((ext_vector_type(4)));
typedef _Float16 h2    __attribute__((ext_vector_type(2)));

#if __has_builtin(__builtin_elementwise_fma)
#define FMA2(a, b, c) __builtin_elementwise_fma((a), (b), (c))
#else
#define FMA2(a, b, c) ((a) * (b) + (c))
#endif

// v_cvt_pkrtz_f16_f32: packs a->low(elt0), b->high(elt1)
__device__ __forceinline__ h2 pkrtz(float a, float b) {
    return __builtin_bit_cast(h2, __builtin_amdgcn_cvt_pkrtz(a, b));
}

// ---- cross-lane primitives ----
// ds_swizzle BitMode: and=offset[4:0], or=offset[9:5], xor=offset[14:10]
template <int PAT>
__device__ __forceinline__ h2 swzh(h2 x) {
    return __builtin_bit_cast(h2, __builtin_amdgcn_ds_swizzle(__builtin_bit_cast(int, x), PAT));
}
// Broadcast qubit q's (c,s) within each 8-lane group: sub on lane bits 0-2,
// group on lane bits 3,4 (bit 5 auto-preserved): and=0x18, or=q  (R1-proven)
#define BCAST_PAT(q) (((q) << 5) | 0x18)
// Butterfly xor4 within 32-half (ISA-doc pattern)
#define SWZ_XOR4 0x101F

template <int CTRL>
__device__ __forceinline__ h2 dpph(h2 x) {
    int i = __builtin_bit_cast(int, x);
    return __builtin_bit_cast(h2, __builtin_amdgcn_update_dpp(i, i, CTRL, 0xF, 0xF, false));
}
#define DPP_XOR1 0xB1   // quad_perm [1,0,3,2]
#define DPP_XOR2 0x4E   // quad_perm [2,3,0,1]

// sign-bit XOR on packed f16 pair (validated by R10==R11 bisect + R17 pass)
__device__ __forceinline__ h2 x2(h2 a, unsigned m) {
    return __builtin_bit_cast(h2, __builtin_bit_cast(unsigned, a) ^ m);
}
// boring half-swap: (lo,hi) -> (hi,lo)
__device__ __forceinline__ h2 hswap(h2 a) {
    return __builtin_shufflevector(a, a, 1, 0);
}
__device__ __forceinline__ h2 splat_lo(h2 a) { h2 r = { a[0], a[0] }; return r; }
__device__ __forceinline__ h2 splat_hi(h2 a) { h2 r = { a[1], a[1] }; return r; }

__global__ __launch_bounds__(64) void qenc_kernel(
    const float* __restrict__ pf,     // [B, 8]
    const float* __restrict__ theta,  // [2, 8]
    const float* __restrict__ scale,  // [8]
    float* __restrict__ out,          // [B, 256]
    int B)
{
    const int lane = threadIdx.x & 63;
    const int sub  = lane & 7;        // qubit-owner index AND idx bits 2..4
    const int g    = lane >> 3;       // batch within wave (8 per wave)

    // T1 XCD-aware swizzle (bijective, nwg=8192 % 8 == 0): consecutive
    // blocks on one XCD now write one contiguous 8 MiB output region,
    // giving each XCD-L2's NT write stream dense HBM locality.
    const int bid  = blockIdx.x;
    const int nper = (int)gridDim.x >> 3;             // 1024 blocks per XCD
    const int swz  = (bid & 7) * nper + (bid >> 3);
    const int bwave = swz * 8;
    const int b     = bwave + g;

    // ---- angles: this lane owns qubit `sub` of batch `b`, both layers ----
    float x  = pf[(size_t)b * 8 + sub];
    float e  = __expf(2.f * x);
    float th = 1.f - 2.f / (e + 1.f);             // tanh(x)
    float b2 = th * (0.5f * PI_F) * scale[sub];
    float h0a = b2 + 0.5f * theta[sub];
    float h1a = b2 + 0.5f * theta[8 + sub];
    h2 cs0 = pkrtz(__cosf(h0a), __sinf(h0a));     // layer-0 (c,s)
    h2 csl = pkrtz(__cosf(h1a), __sinf(h1a));     // layer-1 (c,s)

    // ---- broadcast all 8 qubits' packed (c,s), both layers (16 swizzles) ----
    h2 k0 = swzh<BCAST_PAT(0)>(cs0), k1 = swzh<BCAST_PAT(1)>(cs0);
    h2 k2 = swzh<BCAST_PAT(2)>(cs0), k3 = swzh<BCAST_PAT(3)>(cs0);
    h2 k4 = swzh<BCAST_PAT(4)>(cs0), k5 = swzh<BCAST_PAT(5)>(cs0);
    h2 k6 = swzh<BCAST_PAT(6)>(cs0), k7 = swzh<BCAST_PAT(7)>(cs0);
    h2 q0 = swzh<BCAST_PAT(0)>(csl), q1 = swzh<BCAST_PAT(1)>(csl);
    h2 q2 = swzh<BCAST_PAT(2)>(csl), q3 = swzh<BCAST_PAT(3)>(csl);
    h2 q4 = swzh<BCAST_PAT(4)>(csl), q5 = swzh<BCAST_PAT(5)>(csl);
    h2 q6 = swzh<BCAST_PAT(6)>(csl), q7 = swzh<BCAST_PAT(7)>(csl);

    // ================== layout ==================
    // idx = k*32 + sub*4 + h*2 + p   (k: P-register index 0..7; h: half; p: pack elem)
    // CZ sign terms per R14 decomposition.
    const int   pSL  = __popc(sub & (sub >> 1) & 3) & 1;
    const float SL   = pSL ? -1.f : 1.f;
    const float lam1 = (sub & 1) ? -1.f : 1.f;    // b1b2 factor on h=1
    const float sg4  = (sub & 4) ? -1.f : 1.f;    // b4b5 factor on odd k

    // ---- layer 0 tensor product, CZ#1 folded in f32 (exact) ----
    float G;                                       // qubits 2,3,4 over sub bits
    G  = (sub & 1) ? (float)k2[1] : (float)k2[0];
    G *= (sub & 2) ? (float)k3[1] : (float)k3[0];
    G *= (sub & 4) ? (float)k4[1] : (float)k4[0];
    float Gs = G * SL;

    float f50 = (float)k5[0], f51 = (float)k5[1] * sg4;   // b4b5 folded into f5(1)
    float f60 = (float)k6[0], f61 = (float)k6[1];
    float f70 = (float)k7[0], f71 = (float)k7[1];
    float t0 = Gs * (f50 * f60), t1 = Gs * (f51 * f60);
    float t2 = Gs * (f50 * f61), t3 = Gs * (f51 * f61);
    // W[k] = Gs*H[k]*SK(k)  (SK = -1 at k=3,6)
    const float W[8] = { t0 * f70,  t1 * f70,  t2 * f70, -(t3 * f70),
                         t0 * f71,  t1 * f71, -(t2 * f71), t3 * f71 };

    float m0f = (float)k1[0];           // f1(h=0)
    float m1f = (float)k1[1] * lam1;    // f1(h=1) * b1b2 sign
    h2 k0n = x2(k0, 0x80000000u);       // (c0, -s0): b0b1 sign pre-folded

    h2 P[8][2];
#pragma unroll
    for (int k = 0; k < 8; ++k) {
        h2 wk = pkrtz(W[k] * m0f, W[k] * m1f);
        P[k][0] = splat_lo(wk) * k0;
        P[k][1] = splat_hi(wk) * k0n;
    }

    // ---- layer 1: all 8 gates (commuting) ----
#define PK_KPAIR(KB, cs)                                                      \
    do {                                                                      \
        h2 c2 = splat_lo(cs), s2 = splat_hi(cs);                              \
        _Pragma("unroll")                                                     \
        for (int bse = 0; bse < 8; bse += 2 * (KB)) {                         \
            _Pragma("unroll")                                                 \
            for (int off = 0; off < (KB); ++off) {                            \
                int ka = bse + off, kb = ka + (KB);                           \
                _Pragma("unroll")                                             \
                for (int h = 0; h < 2; ++h) {                                 \
                    h2 a = P[ka][h], bb = P[kb][h];                           \
                    P[ka][h] = FMA2(c2, a, -(s2 * bb));                       \
                    P[kb][h] = FMA2(c2, bb, s2 * a);                          \
                }                                                             \
            }                                                                 \
        }                                                                     \
    } while (0)

#define PK_CROSS(EXCH, BIT, cs)                                               \
    do {                                                                      \
        h2 c2 = splat_lo(cs), s2 = splat_hi(cs);                              \
        h2 se = (sub & (BIT)) ? s2 : -s2;                                     \
        _Pragma("unroll")                                                     \
        for (int k = 0; k < 8; ++k) {                                         \
            _Pragma("unroll")                                                 \
            for (int h = 0; h < 2; ++h) {                                     \
                h2 t = EXCH(P[k][h]);                                         \
                P[k][h] = FMA2(c2, P[k][h], se * t);                          \
            }                                                                 \
        }                                                                     \
    } while (0)

    {   // qubit 0: within-pack butterfly (R12-proven)
        h2 c2 = splat_lo(q0);
        _Float16 sh = q0[1];
        h2 sm = { (_Float16)(-sh), sh };          // (-s, s)
#pragma unroll
        for (int k = 0; k < 8; ++k) {
            P[k][0] = FMA2(c2, P[k][0], sm * hswap(P[k][0]));
            P[k][1] = FMA2(c2, P[k][1], sm * hswap(P[k][1]));
        }
    }
    {   // qubit 1: butterfly between halves h=0 / h=1
        h2 c2 = splat_lo(q1), s2 = splat_hi(q1);
#pragma unroll
        for (int k = 0; k < 8; ++k) {
            h2 a = P[k][0], bb = P[k][1];
            P[k][0] = FMA2(c2, a, -(s2 * bb));
            P[k][1] = FMA2(c2, bb, s2 * a);
        }
    }
    PK_CROSS(dpph<DPP_XOR1>, 1, q2);   // qubit 2 <-> lane bit 0
    PK_CROSS(dpph<DPP_XOR2>, 2, q3);   // qubit 3 <-> lane bit 1
    PK_CROSS(swzh<SWZ_XOR4>, 4, q4);   // qubit 4 <-> lane bit 2
    PK_KPAIR(1, q5);                   // qubit 5 <-> k bit 0
    PK_KPAIR(2, q6);                   // qubit 6 <-> k bit 1
    PK_KPAIR(4, q7);                   // qubit 7 <-> k bit 2

    // ---- CZ#2 as sign-bit XORs (R17-proven) ----
    const unsigned mbase = pSL ? 0x80008000u : 0u;
    const unsigned modd  = mbase ^ ((sub & 4) ? 0x80008000u : 0u);
    const unsigned ml1   = (sub & 1) ? 0x80008000u : 0u;
#pragma unroll
    for (int k = 0; k < 8; ++k) {
        unsigned m0k = ((k & 1) ? modd : mbase)
                     ^ ((k == 3 || k == 6) ? 0x80008000u : 0u);
        unsigned m1k = m0k ^ ml1 ^ 0x80000000u;
        P[k][0] = x2(P[k][0], m0k);
        P[k][1] = x2(P[k][1], m1k);
    }
    // (no normalization: gates orthogonal, ||state|| = 1 within f16 rounding << bf16 tol)

    // ---- direct NT stores: instruction k covers 8 groups x 128B full lines ----
    float* ob = out + (size_t)b * 256 + sub * 4;
#pragma unroll
    for (int k = 0; k < 8; ++k) {
        f32x4 o = { (float)P[k][0][0], (float)P[k][0][1],
                    (float)P[k][1][0], (float)P[k][1][1] };
        __builtin_nontemporal_store(o, reinterpret_cast<f32x4*>(ob + k * 32));
    }
}

extern "C" void kernel_launch(void* const* d_in, const int* in_sizes, int n_in,
                              void* d_out, int out_size, void* d_ws, size_t ws_size,
                              hipStream_t stream) {
    const float* pf    = (const float*)d_in[0];  // [B, 8]
    const float* theta = (const float*)d_in[1];  // [2, 8]
    const float* scale = (const float*)d_in[2];  // [8]
    float* out = (float*)d_out;

    int B = in_sizes[0] / 8;              // 65536
    // R17 structure (one wave/block, 8 batches/wave, 8192 blocks)
    // + T1 XCD swizzle inside the kernel.
    int grid = B / 8;
    qenc_kernel<<<grid, 64, 0, stream>>>(pf, theta, scale, out, B);
}

// Round 20
// 17.451 us; speedup vs baseline: 1.0666x; 1.0666x over previous
//
#include <hip/hip_runtime.h>
#include <math.h>

#define PI_F 3.14159265358979323846f

typedef float    f32x4 __attribute__((ext_vector_type(4)));
typedef _Float16 h2    __attribute__((ext_vector_type(2)));

#if __has_builtin(__builtin_elementwise_fma)
#define FMA2(a, b, c) __builtin_elementwise_fma((a), (b), (c))
#else
#define FMA2(a, b, c) ((a) * (b) + (c))
#endif

// v_cvt_pkrtz_f16_f32: packs a->low(elt0), b->high(elt1)
__device__ __forceinline__ h2 pkrtz(float a, float b) {
    return __builtin_bit_cast(h2, __builtin_amdgcn_cvt_pkrtz(a, b));
}

// ---- cross-lane primitives ----
// ds_swizzle BitMode: and=offset[4:0], or=offset[9:5], xor=offset[14:10]
template <int PAT>
__device__ __forceinline__ h2 swzh(h2 x) {
    return __builtin_bit_cast(h2, __builtin_amdgcn_ds_swizzle(__builtin_bit_cast(int, x), PAT));
}
// sub on lane bits {0,1,3}; group on lane bits {2,4,5}.
// Broadcast from group-lane with sub==q: preserve bits {2,4} (bit5 implicit),
// or places q's bits at lane bits 0,1,3.  (R4..R12-proven pattern)
#define BCAST_PAT(q) (((((q) & 3) | (((q) & 4) << 1)) << 5) | 0x14)

template <int CTRL>
__device__ __forceinline__ h2 dpph(h2 x) {
    int i = __builtin_bit_cast(int, x);
    return __builtin_bit_cast(h2, __builtin_amdgcn_update_dpp(i, i, CTRL, 0xF, 0xF, false));
}
#define DPP_XOR1 0xB1   // quad_perm [1,0,3,2]  : lane^1
#define DPP_XOR2 0x4E   // quad_perm [2,3,0,1]  : lane^2
#define DPP_XOR8 0x128  // row_ror:8            : lane^8 within 16-row

// sign-bit XOR on packed f16 pair (validated R10==R11 bisect + R17 pass)
__device__ __forceinline__ h2 x2(h2 a, unsigned m) {
    return __builtin_bit_cast(h2, __builtin_bit_cast(unsigned, a) ^ m);
}
// half-swap: (lo,hi) -> (hi,lo)
__device__ __forceinline__ h2 hswap(h2 a) {
    return __builtin_shufflevector(a, a, 1, 0);
}
__device__ __forceinline__ h2 splat_lo(h2 a) { h2 r = { a[0], a[0] }; return r; }
__device__ __forceinline__ h2 splat_hi(h2 a) { h2 r = { a[1], a[1] }; return r; }

__global__ __launch_bounds__(64) void qenc_kernel(
    const float* __restrict__ pf,     // [B, 8]
    const float* __restrict__ theta,  // [2, 8]
    const float* __restrict__ scale,  // [8]
    float* __restrict__ out,          // [B, 256]
    int B)
{
    const int lane = threadIdx.x & 63;
    // sub (qubit owner, idx bits 2..4) on lane bits 0,1,3 -> all cross gates DPP
    const int sub  = (lane & 3) | ((lane >> 1) & 4);
    // batch-in-wave on lane bits 2,4,5
    const int g    = ((lane >> 2) & 1) | ((lane >> 3) & 6);

    const int bwave = blockIdx.x * 8; // one 8-batch group per 1-wave block
    const int b     = bwave + g;

    // ---- angles: this lane owns qubit `sub` of batch `b`, both layers ----
    float x  = pf[(size_t)b * 8 + sub];
    float e  = __expf(2.f * x);
    float th = 1.f - 2.f / (e + 1.f);             // tanh(x)
    float b2 = th * (0.5f * PI_F) * scale[sub];
    float h0a = b2 + 0.5f * theta[sub];
    float h1a = b2 + 0.5f * theta[8 + sub];
    h2 cs0 = pkrtz(__cosf(h0a), __sinf(h0a));     // layer-0 (c,s)
    h2 csl = pkrtz(__cosf(h1a), __sinf(h1a));     // layer-1 (c,s)

    // ---- broadcast all 8 qubits' packed (c,s), both layers (16 swizzles,
    //      the ONLY DS ops in the kernel now) ----
    h2 k0 = swzh<BCAST_PAT(0)>(cs0), k1 = swzh<BCAST_PAT(1)>(cs0);
    h2 k2 = swzh<BCAST_PAT(2)>(cs0), k3 = swzh<BCAST_PAT(3)>(cs0);
    h2 k4 = swzh<BCAST_PAT(4)>(cs0), k5 = swzh<BCAST_PAT(5)>(cs0);
    h2 k6 = swzh<BCAST_PAT(6)>(cs0), k7 = swzh<BCAST_PAT(7)>(cs0);
    h2 q0 = swzh<BCAST_PAT(0)>(csl), q1 = swzh<BCAST_PAT(1)>(csl);
    h2 q2 = swzh<BCAST_PAT(2)>(csl), q3 = swzh<BCAST_PAT(3)>(csl);
    h2 q4 = swzh<BCAST_PAT(4)>(csl), q5 = swzh<BCAST_PAT(5)>(csl);
    h2 q6 = swzh<BCAST_PAT(6)>(csl), q7 = swzh<BCAST_PAT(7)>(csl);

    // ================== layout (same algebra as R14..R17) ==================
    // idx = k*32 + sub*4 + h*2 + p ; sub is now a different function of lane,
    // but all CZ/gate algebra depends only on (sub,k,h,p) values -> unchanged.
    const int   pSL  = __popc(sub & (sub >> 1) & 3) & 1;
    const float SL   = pSL ? -1.f : 1.f;
    const float lam1 = (sub & 1) ? -1.f : 1.f;    // b1b2 factor on h=1
    const float sg4  = (sub & 4) ? -1.f : 1.f;    // b4b5 factor on odd k

    // ---- layer 0 tensor product, CZ#1 folded in f32 (exact) ----
    float G;                                       // qubits 2,3,4 over sub bits
    G  = (sub & 1) ? (float)k2[1] : (float)k2[0];
    G *= (sub & 2) ? (float)k3[1] : (float)k3[0];
    G *= (sub & 4) ? (float)k4[1] : (float)k4[0];
    float Gs = G * SL;

    float f50 = (float)k5[0], f51 = (float)k5[1] * sg4;   // b4b5 folded into f5(1)
    float f60 = (float)k6[0], f61 = (float)k6[1];
    float f70 = (float)k7[0], f71 = (float)k7[1];
    float t0 = Gs * (f50 * f60), t1 = Gs * (f51 * f60);
    float t2 = Gs * (f50 * f61), t3 = Gs * (f51 * f61);
    // W[k] = Gs*H[k]*SK(k)  (SK = -1 at k=3,6)
    const float W[8] = { t0 * f70,  t1 * f70,  t2 * f70, -(t3 * f70),
                         t0 * f71,  t1 * f71, -(t2 * f71), t3 * f71 };

    float m0f = (float)k1[0];           // f1(h=0)
    float m1f = (float)k1[1] * lam1;    // f1(h=1) * b1b2 sign
    h2 k0n = x2(k0, 0x80000000u);       // (c0, -s0): b0b1 sign pre-folded

    h2 P[8][2];
#pragma unroll
    for (int k = 0; k < 8; ++k) {
        h2 wk = pkrtz(W[k] * m0f, W[k] * m1f);
        P[k][0] = splat_lo(wk) * k0;
        P[k][1] = splat_hi(wk) * k0n;
    }

    // ---- layer 1: all 8 gates (commuting) ----
#define PK_KPAIR(KB, cs)                                                      \
    do {                                                                      \
        h2 c2 = splat_lo(cs), s2 = splat_hi(cs);                              \
        _Pragma("unroll")                                                     \
        for (int bse = 0; bse < 8; bse += 2 * (KB)) {                         \
            _Pragma("unroll")                                                 \
            for (int off = 0; off < (KB); ++off) {                            \
                int ka = bse + off, kb = ka + (KB);                           \
                _Pragma("unroll")                                             \
                for (int h = 0; h < 2; ++h) {                                 \
                    h2 a = P[ka][h], bb = P[kb][h];                           \
                    P[ka][h] = FMA2(c2, a, -(s2 * bb));                       \
                    P[kb][h] = FMA2(c2, bb, s2 * a);                          \
                }                                                             \
            }                                                                 \
        }                                                                     \
    } while (0)

#define PK_CROSS(CTRL, BIT, cs)                                               \
    do {                                                                      \
        h2 c2 = splat_lo(cs), s2 = splat_hi(cs);                              \
        h2 se = (sub & (BIT)) ? s2 : -s2;                                     \
        _Pragma("unroll")                                                     \
        for (int k = 0; k < 8; ++k) {                                         \
            _Pragma("unroll")                                                 \
            for (int h = 0; h < 2; ++h) {                                     \
                h2 t = dpph<CTRL>(P[k][h]);                                   \
                P[k][h] = FMA2(c2, P[k][h], se * t);                          \
            }                                                                 \
        }                                                                     \
    } while (0)

    {   // qubit 0: within-pack butterfly (R12-proven)
        h2 c2 = splat_lo(q0);
        _Float16 sh = q0[1];
        h2 sm = { (_Float16)(-sh), sh };          // (-s, s)
#pragma unroll
        for (int k = 0; k < 8; ++k) {
            P[k][0] = FMA2(c2, P[k][0], sm * hswap(P[k][0]));
            P[k][1] = FMA2(c2, P[k][1], sm * hswap(P[k][1]));
        }
    }
    {   // qubit 1: butterfly between halves h=0 / h=1
        h2 c2 = splat_lo(q1), s2 = splat_hi(q1);
#pragma unroll
        for (int k = 0; k < 8; ++k) {
            h2 a = P[k][0], bb = P[k][1];
            P[k][0] = FMA2(c2, a, -(s2 * bb));
            P[k][1] = FMA2(c2, bb, s2 * a);
        }
    }
    PK_CROSS(DPP_XOR1, 1, q2);   // qubit 2 <-> lane bit 0 (sub bit 0)
    PK_CROSS(DPP_XOR2, 2, q3);   // qubit 3 <-> lane bit 1 (sub bit 1)
    PK_CROSS(DPP_XOR8, 4, q4);   // qubit 4 <-> lane bit 3 (sub bit 2)
    PK_KPAIR(1, q5);             // qubit 5 <-> k bit 0
    PK_KPAIR(2, q6);             // qubit 6 <-> k bit 1
    PK_KPAIR(4, q7);             // qubit 7 <-> k bit 2

    // ---- CZ#2 as sign-bit XORs (R17-proven) ----
    const unsigned mbase = pSL ? 0x80008000u : 0u;
    const unsigned modd  = mbase ^ ((sub & 4) ? 0x80008000u : 0u);
    const unsigned ml1   = (sub & 1) ? 0x80008000u : 0u;
#pragma unroll
    for (int k = 0; k < 8; ++k) {
        unsigned m0k = ((k & 1) ? modd : mbase)
                     ^ ((k == 3 || k == 6) ? 0x80008000u : 0u);
        unsigned m1k = m0k ^ ml1 ^ 0x80000000u;
        P[k][0] = x2(P[k][0], m0k);
        P[k][1] = x2(P[k][1], m1k);
    }
    // (no normalization: gates orthogonal, ||state|| = 1 within f16 rounding << bf16 tol)

    // ---- direct NT stores: same address SET as R17 (16 full 64B lines per
    //      instruction), lane->address mapping permuted by the sub remap ----
    float* ob = out + (size_t)b * 256 + sub * 4;
#pragma unroll
    for (int k = 0; k < 8; ++k) {
        f32x4 o = { (float)P[k][0][0], (float)P[k][0][1],
                    (float)P[k][1][0], (float)P[k][1][1] };
        __builtin_nontemporal_store(o, reinterpret_cast<f32x4*>(ob + k * 32));
    }
}

extern "C" void kernel_launch(void* const* d_in, const int* in_sizes, int n_in,
                              void* d_out, int out_size, void* d_ws, size_t ws_size,
                              hipStream_t stream) {
    const float* pf    = (const float*)d_in[0];  // [B, 8]
    const float* theta = (const float*)d_in[1];  // [2, 8]
    const float* scale = (const float*)d_in[2];  // [8]
    float* out = (float*)d_out;

    int B = in_sizes[0] / 8;              // 65536
    // R17 structure: one wave per block, 8 batches per wave, 8192 blocks
    int grid = B / 8;
    qenc_kernel<<<grid, 64, 0, stream>>>(pf, theta, scale, out, B);
}